// Round 2
// baseline (424.968 us; speedup 1.0000x reference)
//
#include <hip/hip_runtime.h>

// B=32, DIM=4096, NH=32, NKV=8, HD=128, MAXLEN=4096, START_POS=4095. All fp32.
// Roofline: KV 1GB + weights 160MB -> ~190us @6.3TB/s.
#define MAXLEN 4096
#define QSCALE 0.08838834764831845f   // 1/sqrt(128)

// ws layout (floats):
//  part_qkv [8][32][6144]   @ 0        (1572864)
//  pmss     [256*2*4][2]    @ 1572864  (4096)
//  pacc     [256*2*4][128]  @ 1576960  (262144)
//  a_ws     [32][4096]      @ 1839104  (131072)
//  part_out [8][32][4096]   @ 1970176  (1048576)

// ---------------------------------------------------------------------------
// GEMV core: part[b][mg+m] partial over K-slice ks (512 k), Mtile=64 rows.
// 256 thr = 4 waves; wave owns 128 k (8 chunks x 16 k). Thread tile 8r x 8b,
// k-halved across lane>>5, shfl-reduced. LDS: k-interleaved pitch-100 tiles
// (conflict-free b128 reads), reg-staged prefetch of next chunk.
// ---------------------------------------------------------------------------
__device__ __forceinline__ void gemv_core2(
    const float* __restrict__ W, const int mw,
    const float* __restrict__ X,
    float* __restrict__ partS, const int M, const int mg, const int ks)
{
    const int t = threadIdx.x;
    const int wave = t >> 6, lane = t & 63;
    const int khalf = lane >> 5;
    const int p = lane & 31;
    const int tr = p & 7, tb = p >> 3;
    const int xb = lane & 31;

    __shared__ union {
        float stage[4][16][100];
        float red[4][64][33];
    } u;

    float acc[8][8];
#pragma unroll
    for (int r = 0; r < 8; ++r)
#pragma unroll
        for (int c = 0; c < 8; ++c) acc[r][c] = 0.f;

    const int k0 = ks * 512 + wave * 128;
    const float* Wp = W + (size_t)(mw + lane) * 4096 + k0;
    const float* Xp = X + (size_t)xb * 4096 + k0 + khalf * 8;
    float* sw = &u.stage[wave][0][0];
    float* sx = sw + 64 + xb;
    const int xo = khalf;

    float4 wr0 = *(const float4*)(Wp + 0);
    float4 wr1 = *(const float4*)(Wp + 4);
    float4 wr2 = *(const float4*)(Wp + 8);
    float4 wr3 = *(const float4*)(Wp + 12);
    float4 xr0 = *(const float4*)(Xp + 0);
    float4 xr1 = *(const float4*)(Xp + 4);

#pragma unroll
    for (int c = 0; c < 8; ++c) {
        // ---- LDS write current chunk (k-interleaved: kk = ((k&7)<<1)|(k>>3))
        sw[0*100+lane]=wr0.x;  sw[2*100+lane]=wr0.y;  sw[4*100+lane]=wr0.z;  sw[6*100+lane]=wr0.w;
        sw[8*100+lane]=wr1.x;  sw[10*100+lane]=wr1.y; sw[12*100+lane]=wr1.z; sw[14*100+lane]=wr1.w;
        sw[1*100+lane]=wr2.x;  sw[3*100+lane]=wr2.y;  sw[5*100+lane]=wr2.z;  sw[7*100+lane]=wr2.w;
        sw[9*100+lane]=wr3.x;  sw[11*100+lane]=wr3.y; sw[13*100+lane]=wr3.z; sw[15*100+lane]=wr3.w;
        sx[(0+xo)*100]=xr0.x;  sx[(2+xo)*100]=xr0.y;  sx[(4+xo)*100]=xr0.z;  sx[(6+xo)*100]=xr0.w;
        sx[(8+xo)*100]=xr1.x;  sx[(10+xo)*100]=xr1.y; sx[(12+xo)*100]=xr1.z; sx[(14+xo)*100]=xr1.w;

        // ---- prefetch next chunk (latency hides under compute)
        float4 nw0, nw1, nw2, nw3, nx0, nx1;
        if (c < 7) {
            const float* wn = Wp + (c + 1) * 16;
            const float* xn = Xp + (c + 1) * 16;
            nw0 = *(const float4*)(wn + 0);
            nw1 = *(const float4*)(wn + 4);
            nw2 = *(const float4*)(wn + 8);
            nw3 = *(const float4*)(wn + 12);
            nx0 = *(const float4*)(xn + 0);
            nx1 = *(const float4*)(xn + 4);
        }

        // ---- compute chunk (thread handles k = c*16 + khalf*8 + k8)
#pragma unroll
        for (int k8 = 0; k8 < 8; ++k8) {
            const float* row = sw + (k8 * 2 + khalf) * 100;
            const float4 wa = *(const float4*)(row + tr * 8);
            const float4 wb = *(const float4*)(row + tr * 8 + 4);
            const float4 xa = *(const float4*)(row + 64 + tb * 8);
            const float4 xc = *(const float4*)(row + 64 + tb * 8 + 4);
            const float wv[8] = {wa.x, wa.y, wa.z, wa.w, wb.x, wb.y, wb.z, wb.w};
            const float xv[8] = {xa.x, xa.y, xa.z, xa.w, xc.x, xc.y, xc.z, xc.w};
#pragma unroll
            for (int r = 0; r < 8; ++r)
#pragma unroll
                for (int cc = 0; cc < 8; ++cc)
                    acc[r][cc] = fmaf(wv[r], xv[cc], acc[r][cc]);
        }
        if (c < 7) { wr0 = nw0; wr1 = nw1; wr2 = nw2; wr3 = nw3; xr0 = nx0; xr1 = nx1; }
    }

    // ---- khalf reduce in-wave
#pragma unroll
    for (int r = 0; r < 8; ++r)
#pragma unroll
        for (int cc = 0; cc < 8; ++cc)
            acc[r][cc] += __shfl_xor(acc[r][cc], 32);

    __syncthreads();   // all waves done with stage (union aliasing)
    float* rd = &u.red[0][0][0];
    if (khalf == 0) {
#pragma unroll
        for (int r = 0; r < 8; ++r)
#pragma unroll
            for (int cc = 0; cc < 8; ++cc)
                rd[wave * 2112 + (tr * 8 + r) * 33 + tb * 8 + cc] = acc[r][cc];
    }
    __syncthreads();

    // ---- cross-wave sum + write: thread -> (batch fb, 8 consecutive m)
    const int fb = t >> 3, mgrp = t & 7;
    float s[8];
#pragma unroll
    for (int e = 0; e < 8; ++e) {
        const int ml = mgrp * 8 + e;
        s[e] = rd[0 * 2112 + ml * 33 + fb] + rd[1 * 2112 + ml * 33 + fb]
             + rd[2 * 2112 + ml * 33 + fb] + rd[3 * 2112 + ml * 33 + fb];
    }
    float* dst = partS + (size_t)fb * M + mg + mgrp * 8;
    *(float4*)dst       = make_float4(s[0], s[1], s[2], s[3]);
    *(float4*)(dst + 4) = make_float4(s[4], s[5], s[6], s[7]);
}

__global__ __launch_bounds__(256, 3) void gemv_qkv_kernel(
    const float* __restrict__ wq, const float* __restrict__ wk,
    const float* __restrict__ wv, const float* __restrict__ x,
    float* __restrict__ part)     // [8][32][6144]
{
    const int mb = blockIdx.x >> 3, ks = blockIdx.x & 7;
    const int m0 = mb * 64;
    const float* W; int mw;
    if (m0 < 4096)      { W = wq; mw = m0; }
    else if (m0 < 5120) { W = wk; mw = m0 - 4096; }
    else                { W = wv; mw = m0 - 5120; }
    gemv_core2(W, mw, x, part + (size_t)ks * (32 * 6144), 6144, m0, ks);
}

__global__ __launch_bounds__(256, 3) void gemv_out_kernel(
    const float* __restrict__ wo, const float* __restrict__ a_ws,
    float* __restrict__ part)     // [8][32][4096]
{
    const int mb = blockIdx.x >> 3, ks = blockIdx.x & 7;
    gemv_core2(wo, mb * 64, a_ws, part + (size_t)ks * (32 * 4096), 4096, mb * 64, ks);
}

// ---------------------------------------------------------------------------
// Attention: grid 512 = (b,g) x 2 seq-splits. 256 thr = 4 waves = 32 groups
// of 8 lanes; group handles one row/step (4 float4/lane, 128B/group segments).
// Online softmax w/ deferred rescale; 3-level shfl dot-reduce; epilogue row
// 4095 = roped new token from LDS. Partials (m, ss, acc) to ws.
// ---------------------------------------------------------------------------
__device__ __forceinline__ float dot16(const float4* q, const float4* k, float acc0)
{
    float d = acc0;
    d = fmaf(q[0].x, k[0].x, d); d = fmaf(q[0].y, k[0].y, d);
    d = fmaf(q[0].z, k[0].z, d); d = fmaf(q[0].w, k[0].w, d);
    d = fmaf(q[1].x, k[1].x, d); d = fmaf(q[1].y, k[1].y, d);
    d = fmaf(q[1].z, k[1].z, d); d = fmaf(q[1].w, k[1].w, d);
    d = fmaf(q[2].x, k[2].x, d); d = fmaf(q[2].y, k[2].y, d);
    d = fmaf(q[2].z, k[2].z, d); d = fmaf(q[2].w, k[2].w, d);
    d = fmaf(q[3].x, k[3].x, d); d = fmaf(q[3].y, k[3].y, d);
    d = fmaf(q[3].z, k[3].z, d); d = fmaf(q[3].w, k[3].w, d);
    return d;
}

__global__ __launch_bounds__(256, 2) void attn2_kernel(
    const float* __restrict__ part_qkv,   // [8][32][6144]
    const float* __restrict__ freqs,      // [128]
    const float* __restrict__ cache_k, const float* __restrict__ cache_v,
    float* __restrict__ pmss,             // [256*2*4][2]
    float* __restrict__ pacc)             // [256*2*4][128]
{
    const int t = threadIdx.x;
    const int bg = blockIdx.x >> 1, split = blockIdx.x & 1;
    const int b = bg >> 3, g = bg & 7;
    const int wave = t >> 6, lane = t & 63;
    const int j = lane & 7, g8 = lane >> 3;
    const int bgi = wave * 8 + g8;

    __shared__ float qc[4][128];
    __shared__ float knv[2][128];
    __shared__ float wacc[4][4][128];
    __shared__ float wm[4][4], wss[4][4];

    const size_t PS = 32 * 6144;
    // ---- prologue: sum 8 qkv partials; rope q (scaled) and new k ----
    if (t < 128) {
        const int h = t >> 5, d0 = (t & 31) * 4;
        const float* pq = part_qkv + (size_t)b * 6144 + (size_t)(g * 4 + h) * 128 + d0;
        float4 sv = make_float4(0.f, 0.f, 0.f, 0.f);
#pragma unroll
        for (int s = 0; s < 8; ++s) {
            const float4 pv = *(const float4*)(pq + s * PS);
            sv.x += pv.x; sv.y += pv.y; sv.z += pv.z; sv.w += pv.w;
        }
        const float4 f = *(const float4*)(freqs + d0);
        qc[h][d0 + 0] = (sv.x * f.x - sv.y * f.y) * QSCALE;
        qc[h][d0 + 1] = (sv.x * f.y + sv.y * f.x) * QSCALE;
        qc[h][d0 + 2] = (sv.z * f.z - sv.w * f.w) * QSCALE;
        qc[h][d0 + 3] = (sv.z * f.w + sv.w * f.z) * QSCALE;
    } else if (t < 160) {
        const int d0 = (t - 128) * 4;
        const float* pk = part_qkv + (size_t)b * 6144 + 4096 + g * 128 + d0;
        const float* pv = part_qkv + (size_t)b * 6144 + 5120 + g * 128 + d0;
        float4 kv = make_float4(0.f, 0.f, 0.f, 0.f);
        float4 vv = make_float4(0.f, 0.f, 0.f, 0.f);
#pragma unroll
        for (int s = 0; s < 8; ++s) {
            const float4 a = *(const float4*)(pk + s * PS);
            const float4 c = *(const float4*)(pv + s * PS);
            kv.x += a.x; kv.y += a.y; kv.z += a.z; kv.w += a.w;
            vv.x += c.x; vv.y += c.y; vv.z += c.z; vv.w += c.w;
        }
        const float4 f = *(const float4*)(freqs + d0);
        knv[0][d0 + 0] = kv.x * f.x - kv.y * f.y;
        knv[0][d0 + 1] = kv.x * f.y + kv.y * f.x;
        knv[0][d0 + 2] = kv.z * f.z - kv.w * f.w;
        knv[0][d0 + 3] = kv.z * f.w + kv.w * f.z;
        knv[1][d0 + 0] = vv.x; knv[1][d0 + 1] = vv.y;
        knv[1][d0 + 2] = vv.z; knv[1][d0 + 3] = vv.w;
    }
    __syncthreads();

    float4 q[4][4];
#pragma unroll
    for (int h = 0; h < 4; ++h)
#pragma unroll
        for (int i = 0; i < 4; ++i)
            q[h][i] = *(const float4*)&qc[h][j * 4 + i * 32];

    float m[4] = {-1e30f, -1e30f, -1e30f, -1e30f};
    float ss[4] = {0.f, 0.f, 0.f, 0.f};
    float4 acc[4][4];
#pragma unroll
    for (int h = 0; h < 4; ++h)
#pragma unroll
        for (int i = 0; i < 4; ++i)
            acc[h][i] = make_float4(0.f, 0.f, 0.f, 0.f);

    const size_t rowbase = (size_t)(split * 2048 + wave * 8 + g8) * 1024 + g * 128 + j * 4;
    const float* kp = cache_k + (size_t)b * MAXLEN * 1024 + rowbase;
    const float* vp = cache_v + (size_t)b * MAXLEN * 1024 + rowbase;

    auto process = [&](const float4* kf, const float4* vf) {
#pragma unroll
        for (int h = 0; h < 4; ++h) {
            float d = dot16(q[h], kf, 0.f);
            d += __shfl_xor(d, 1);
            d += __shfl_xor(d, 2);
            d += __shfl_xor(d, 4);
            const float dd = d - m[h];
            float pe;
            if (dd > 8.0f) {                       // rare: new max by margin
                const float c = __expf(-dd);
                ss[h] = fmaf(ss[h], c, 1.0f);
#pragma unroll
                for (int i = 0; i < 4; ++i) {
                    acc[h][i].x *= c; acc[h][i].y *= c;
                    acc[h][i].z *= c; acc[h][i].w *= c;
                }
                m[h] = d; pe = 1.0f;
            } else {
                pe = __expf(dd);                   // <= e^8
                ss[h] += pe;
            }
#pragma unroll
            for (int i = 0; i < 4; ++i) {
                acc[h][i].x = fmaf(pe, vf[i].x, acc[h][i].x);
                acc[h][i].y = fmaf(pe, vf[i].y, acc[h][i].y);
                acc[h][i].z = fmaf(pe, vf[i].z, acc[h][i].z);
                acc[h][i].w = fmaf(pe, vf[i].w, acc[h][i].w);
            }
        }
    };

    const int iters = split ? 63 : 64;
#pragma unroll 2
    for (int it = 0; it < iters; ++it) {
        float4 kf[4], vf[4];
#pragma unroll
        for (int i = 0; i < 4; ++i) {
            kf[i] = *(const float4*)(kp + i * 32);
            vf[i] = *(const float4*)(vp + i * 32);
        }
        kp += 32 * 1024; vp += 32 * 1024;
        process(kf, vf);
    }
    if (split) {   // rows 4064..4095; group 31 = new token (row 4095)
        float4 kf[4], vf[4];
        if (bgi == 31) {
#pragma unroll
            for (int i = 0; i < 4; ++i) {
                kf[i] = *(const float4*)&knv[0][j * 4 + i * 32];
                vf[i] = *(const float4*)&knv[1][j * 4 + i * 32];
            }
        } else {
#pragma unroll
            for (int i = 0; i < 4; ++i) {
                kf[i] = *(const float4*)(kp + i * 32);
                vf[i] = *(const float4*)(vp + i * 32);
            }
        }
        process(kf, vf);
    }

    // ---- merge 8 groups within wave (xor 8,16,32) ----
#pragma unroll
    for (int off = 8; off <= 32; off <<= 1) {
#pragma unroll
        for (int h = 0; h < 4; ++h) {
            const float m2 = __shfl_xor(m[h], off);
            const float s2 = __shfl_xor(ss[h], off);
            float4 a2[4];
#pragma unroll
            for (int i = 0; i < 4; ++i) {
                a2[i].x = __shfl_xor(acc[h][i].x, off);
                a2[i].y = __shfl_xor(acc[h][i].y, off);
                a2[i].z = __shfl_xor(acc[h][i].z, off);
                a2[i].w = __shfl_xor(acc[h][i].w, off);
            }
            const float M2 = fmaxf(m[h], m2);
            const float c1 = __expf(m[h] - M2), c2 = __expf(m2 - M2);
            ss[h] = ss[h] * c1 + s2 * c2;
#pragma unroll
            for (int i = 0; i < 4; ++i) {
                acc[h][i].x = acc[h][i].x * c1 + a2[i].x * c2;
                acc[h][i].y = acc[h][i].y * c1 + a2[i].y * c2;
                acc[h][i].z = acc[h][i].z * c1 + a2[i].z * c2;
                acc[h][i].w = acc[h][i].w * c1 + a2[i].w * c2;
            }
            m[h] = M2;
        }
    }

    if (g8 == 0) {
#pragma unroll
        for (int h = 0; h < 4; ++h)
#pragma unroll
            for (int i = 0; i < 4; ++i)
                *(float4*)&wacc[wave][h][j * 4 + i * 32] = acc[h][i];
        if (j == 0)
#pragma unroll
            for (int h = 0; h < 4; ++h) { wm[wave][h] = m[h]; wss[wave][h] = ss[h]; }
    }
    __syncthreads();

    if (t < 128) {
        const int h = t >> 5, jj = t & 31;
        const float M = fmaxf(fmaxf(wm[0][h], wm[1][h]), fmaxf(wm[2][h], wm[3][h]));
        const float c0 = __expf(wm[0][h] - M), c1 = __expf(wm[1][h] - M);
        const float c2 = __expf(wm[2][h] - M), c3 = __expf(wm[3][h] - M);
        const float SS = wss[0][h] * c0 + wss[1][h] * c1 + wss[2][h] * c2 + wss[3][h] * c3;
        const float4 a0 = *(const float4*)&wacc[0][h][jj * 4];
        const float4 a1 = *(const float4*)&wacc[1][h][jj * 4];
        const float4 a2 = *(const float4*)&wacc[2][h][jj * 4];
        const float4 a3 = *(const float4*)&wacc[3][h][jj * 4];
        float4 o;
        o.x = a0.x * c0 + a1.x * c1 + a2.x * c2 + a3.x * c3;
        o.y = a0.y * c0 + a1.y * c1 + a2.y * c2 + a3.y * c3;
        o.z = a0.z * c0 + a1.z * c1 + a2.z * c2 + a3.z * c3;
        o.w = a0.w * c0 + a1.w * c1 + a2.w * c2 + a3.w * c3;
        const int pi = (bg * 2 + split) * 4 + h;
        if (jj == 0) { pmss[pi * 2] = M; pmss[pi * 2 + 1] = SS; }
        *(float4*)&pacc[pi * 128 + jj * 4] = o;
    }
}

__global__ __launch_bounds__(128) void attn_combine_kernel(
    const float* __restrict__ pmss, const float* __restrict__ pacc,
    float* __restrict__ a_ws)
{
    const int bg = blockIdx.x, t = threadIdx.x;
    const int h = t >> 5, jj = t & 31;
    const int b = bg >> 3, g = bg & 7;
    const int p0 = (bg * 2 + 0) * 4 + h, p1 = (bg * 2 + 1) * 4 + h;
    const float m0 = pmss[p0 * 2], s0 = pmss[p0 * 2 + 1];
    const float m1 = pmss[p1 * 2], s1 = pmss[p1 * 2 + 1];
    const float M = fmaxf(m0, m1);
    const float c0 = __expf(m0 - M), c1 = __expf(m1 - M);
    const float inv = 1.f / (s0 * c0 + s1 * c1);
    const float4 a0 = *(const float4*)&pacc[p0 * 128 + jj * 4];
    const float4 a1 = *(const float4*)&pacc[p1 * 128 + jj * 4];
    float4 o;
    o.x = (a0.x * c0 + a1.x * c1) * inv;
    o.y = (a0.y * c0 + a1.y * c1) * inv;
    o.z = (a0.z * c0 + a1.z * c1) * inv;
    o.w = (a0.w * c0 + a1.w * c1) * inv;
    *(float4*)&a_ws[(size_t)b * 4096 + (size_t)(g * 4 + h) * 128 + jj * 4] = o;
}

__global__ __launch_bounds__(256) void out_combine_kernel(
    const float* __restrict__ part, float* __restrict__ out)
{
    const int i4 = (blockIdx.x * 256 + threadIdx.x) * 4;
    float4 v = make_float4(0.f, 0.f, 0.f, 0.f);
#pragma unroll
    for (int s = 0; s < 8; ++s) {
        const float4 a = *(const float4*)(part + (size_t)s * 131072 + i4);
        v.x += a.x; v.y += a.y; v.z += a.z; v.w += a.w;
    }
    *(float4*)(out + i4) = v;
}

extern "C" void kernel_launch(void* const* d_in, const int* in_sizes, int n_in,
                              void* d_out, int out_size, void* d_ws, size_t ws_size,
                              hipStream_t stream)
{
    const float* x       = (const float*)d_in[0];
    const float* freqs   = (const float*)d_in[1];
    const float* cache_k = (const float*)d_in[2];
    const float* cache_v = (const float*)d_in[3];
    const float* wq      = (const float*)d_in[4];
    const float* wk      = (const float*)d_in[5];
    const float* wv      = (const float*)d_in[6];
    const float* wo      = (const float*)d_in[7];

    float* out = (float*)d_out;
    float* ws  = (float*)d_ws;
    float* part_qkv = ws;                     // 1572864
    float* pmss     = ws + 1572864;           // 4096
    float* pacc     = ws + 1576960;           // 262144
    float* a_ws     = ws + 1839104;           // 131072
    float* part_out = ws + 1970176;           // 1048576

    gemv_qkv_kernel<<<768, 256, 0, stream>>>(wq, wk, wv, x, part_qkv);
    attn2_kernel<<<512, 256, 0, stream>>>(part_qkv, freqs, cache_k, cache_v, pmss, pacc);
    attn_combine_kernel<<<256, 128, 0, stream>>>(pmss, pacc, a_ws);
    gemv_out_kernel<<<512, 256, 0, stream>>>(wo, a_ws, part_out);
    out_combine_kernel<<<128, 256, 0, stream>>>(part_out, out);
}

// Round 3
// 350.198 us; speedup vs baseline: 1.2135x; 1.2135x over previous
//
#include <hip/hip_runtime.h>

// B=32, DIM=4096, NH=32, NKV=8, HD=128, MAXLEN=4096, START_POS=4095. All fp32.
// HBM floor: KV 1GB + weights 160MB ~= 190us @6.3TB/s.
#define QSCALE 0.08838834764831845f   // 1/sqrt(128)

// ws layout (floats):
//  part_qkv [16][32][6144] @ 0          (3145728)
//  qc_g     [32][4096]     @ 3145728    (131072)   roped+scaled q
//  kn_g     [32][1024]     @ 3276800    (32768)    roped new k
//  vn_g     [32][1024]     @ 3309568    (32768)    new v
//  pmss     [65536][2]     @ 3342336    (131072)
//  pacc     [65536][128]   @ 3473408    (8388608)
//  a_ws     [32][4096]     @ 11862016   (131072)
//  part_out [16][32][4096] @ 11993088   (2097152)

// ---------------------------------------------------------------------------
// GEMV: part[ks][n][m0+..] = sum over 256-k slice of W[m][k]*X[n][k].
// 256 thr: ksub=t&3 (k quads), ngrp=(t>>2)&7 (4 n each), mgrp=t>>5 (8 m each).
// W loads: 4 ksub lanes x float4 = 64B contiguous per row, 2 rows/instr.
// No LDS. acc 8x4 in regs; shfl-reduce over ksub; ksub==0 lanes store.
// ---------------------------------------------------------------------------
#define GEMM_FMA(r, wf) \
    acc[r][0] = fmaf(wf.x, x0.x, acc[r][0]); acc[r][0] = fmaf(wf.y, x0.y, acc[r][0]); \
    acc[r][0] = fmaf(wf.z, x0.z, acc[r][0]); acc[r][0] = fmaf(wf.w, x0.w, acc[r][0]); \
    acc[r][1] = fmaf(wf.x, x1.x, acc[r][1]); acc[r][1] = fmaf(wf.y, x1.y, acc[r][1]); \
    acc[r][1] = fmaf(wf.z, x1.z, acc[r][1]); acc[r][1] = fmaf(wf.w, x1.w, acc[r][1]); \
    acc[r][2] = fmaf(wf.x, x2.x, acc[r][2]); acc[r][2] = fmaf(wf.y, x2.y, acc[r][2]); \
    acc[r][2] = fmaf(wf.z, x2.z, acc[r][2]); acc[r][2] = fmaf(wf.w, x2.w, acc[r][2]); \
    acc[r][3] = fmaf(wf.x, x3.x, acc[r][3]); acc[r][3] = fmaf(wf.y, x3.y, acc[r][3]); \
    acc[r][3] = fmaf(wf.z, x3.z, acc[r][3]); acc[r][3] = fmaf(wf.w, x3.w, acc[r][3]);

__device__ __forceinline__ void gemv3(
    const float* __restrict__ W,      // pre-offset: row 0 == output column m0
    const float* __restrict__ X,
    float* __restrict__ part, const int M, const int m0, const int ks)
{
    const int t = threadIdx.x;
    const int ksub = t & 3;
    const int ngrp = (t >> 2) & 7;
    const int mgrp = t >> 5;

    const int kbase = ks * 256 + ksub * 4;
    const float* wr0 = W + (size_t)(mgrp * 8 + 0) * 4096 + kbase;
    const float* wr1 = W + (size_t)(mgrp * 8 + 1) * 4096 + kbase;
    const float* wr2 = W + (size_t)(mgrp * 8 + 2) * 4096 + kbase;
    const float* wr3 = W + (size_t)(mgrp * 8 + 3) * 4096 + kbase;
    const float* wr4 = W + (size_t)(mgrp * 8 + 4) * 4096 + kbase;
    const float* wr5 = W + (size_t)(mgrp * 8 + 5) * 4096 + kbase;
    const float* wr6 = W + (size_t)(mgrp * 8 + 6) * 4096 + kbase;
    const float* wr7 = W + (size_t)(mgrp * 8 + 7) * 4096 + kbase;
    const float* xr0 = X + (size_t)(ngrp * 4 + 0) * 4096 + kbase;
    const float* xr1 = X + (size_t)(ngrp * 4 + 1) * 4096 + kbase;
    const float* xr2 = X + (size_t)(ngrp * 4 + 2) * 4096 + kbase;
    const float* xr3 = X + (size_t)(ngrp * 4 + 3) * 4096 + kbase;

    float acc[8][4];
#pragma unroll
    for (int r = 0; r < 8; ++r)
#pragma unroll
        for (int n = 0; n < 4; ++n) acc[r][n] = 0.f;

#pragma unroll 2
    for (int c = 0; c < 16; ++c) {
        const int off = c * 16;
        const float4 w0 = *(const float4*)(wr0 + off);
        const float4 w1 = *(const float4*)(wr1 + off);
        const float4 w2 = *(const float4*)(wr2 + off);
        const float4 w3 = *(const float4*)(wr3 + off);
        const float4 w4 = *(const float4*)(wr4 + off);
        const float4 w5 = *(const float4*)(wr5 + off);
        const float4 w6 = *(const float4*)(wr6 + off);
        const float4 w7 = *(const float4*)(wr7 + off);
        const float4 x0 = *(const float4*)(xr0 + off);
        const float4 x1 = *(const float4*)(xr1 + off);
        const float4 x2 = *(const float4*)(xr2 + off);
        const float4 x3 = *(const float4*)(xr3 + off);
        GEMM_FMA(0, w0) GEMM_FMA(1, w1) GEMM_FMA(2, w2) GEMM_FMA(3, w3)
        GEMM_FMA(4, w4) GEMM_FMA(5, w5) GEMM_FMA(6, w6) GEMM_FMA(7, w7)
    }

    // reduce over the 4 ksub lanes (lane bits 0-1)
#pragma unroll
    for (int r = 0; r < 8; ++r)
#pragma unroll
        for (int n = 0; n < 4; ++n) {
            acc[r][n] += __shfl_xor(acc[r][n], 1);
            acc[r][n] += __shfl_xor(acc[r][n], 2);
        }

    if (ksub == 0) {
        float* base = part + (size_t)ks * 32 * M + m0 + mgrp * 8;
#pragma unroll
        for (int n = 0; n < 4; ++n) {
            float* dst = base + (size_t)(ngrp * 4 + n) * M;
            *(float4*)(dst)     = make_float4(acc[0][n], acc[1][n], acc[2][n], acc[3][n]);
            *(float4*)(dst + 4) = make_float4(acc[4][n], acc[5][n], acc[6][n], acc[7][n]);
        }
    }
}

__global__ __launch_bounds__(256, 4) void gemv_qkv_kernel(
    const float* __restrict__ wq, const float* __restrict__ wk,
    const float* __restrict__ wv, const float* __restrict__ x,
    float* __restrict__ part)     // [16][32][6144]
{
    const int mb = blockIdx.x >> 4, ks = blockIdx.x & 15;
    const int m0 = mb * 64;
    const float* W;
    if (m0 < 4096)      W = wq + (size_t)m0 * 4096;
    else if (m0 < 5120) W = wk + (size_t)(m0 - 4096) * 4096;
    else                W = wv + (size_t)(m0 - 5120) * 4096;
    gemv3(W, x, part, 6144, m0, ks);
}

__global__ __launch_bounds__(256, 4) void gemv_out_kernel(
    const float* __restrict__ wo, const float* __restrict__ a_ws,
    float* __restrict__ part)     // [16][32][4096]
{
    const int mb = blockIdx.x >> 4, ks = blockIdx.x & 15;
    gemv3(wo + (size_t)(mb * 64) * 4096, a_ws, part, 4096, mb * 64, ks);
}

// ---------------------------------------------------------------------------
// qkv combine: sum 16 k-split partials; rope+scale q, rope new k, copy new v.
// ---------------------------------------------------------------------------
__global__ __launch_bounds__(256) void qkv_combine_kernel(
    const float* __restrict__ part,   // [16][32][6144]
    const float* __restrict__ freqs,  // [128]
    float* __restrict__ qc_g, float* __restrict__ kn_g, float* __restrict__ vn_g)
{
    const int idx = blockIdx.x * 256 + threadIdx.x;   // f4 index, 49152 total
    const int b = idx / 1536;
    const int cm = (idx - b * 1536) * 4;              // column within 6144
    const float* p = part + (size_t)b * 6144 + cm;
    float4 v = make_float4(0.f, 0.f, 0.f, 0.f);
#pragma unroll
    for (int s = 0; s < 16; ++s) {
        const float4 a = *(const float4*)(p + (size_t)s * (32 * 6144));
        v.x += a.x; v.y += a.y; v.z += a.z; v.w += a.w;
    }
    if (cm < 4096) {
        const int d = cm & 127;
        const float4 f = *(const float4*)(freqs + d);
        float4 o;
        o.x = (v.x * f.x - v.y * f.y) * QSCALE;
        o.y = (v.x * f.y + v.y * f.x) * QSCALE;
        o.z = (v.z * f.z - v.w * f.w) * QSCALE;
        o.w = (v.z * f.w + v.w * f.z) * QSCALE;
        *(float4*)(qc_g + (size_t)b * 4096 + cm) = o;
    } else if (cm < 5120) {
        const int d = (cm - 4096) & 127;
        const float4 f = *(const float4*)(freqs + d);
        float4 o;
        o.x = v.x * f.x - v.y * f.y;
        o.y = v.x * f.y + v.y * f.x;
        o.z = v.z * f.z - v.w * f.w;
        o.w = v.z * f.w + v.w * f.z;
        *(float4*)(kn_g + (size_t)b * 1024 + (cm - 4096)) = o;
    } else {
        *(float4*)(vn_g + (size_t)b * 1024 + (cm - 5120)) = v;
    }
}

// ---------------------------------------------------------------------------
// Attention: block=(b, split of 512 rows), 512 thr = 8 waves, wave = 64
// consecutive rows. A wave reads FULL 4KB cache rows (all 8 g at once):
// lane g8=lane>>3, j=lane&7 owns 16 floats {g8*128 + p*32 + j*4}.
// Per instr: 8 x 128B contiguous segments; rows sequential -> pure stream.
// Online softmax (deferred rescale); 3-shfl dot reduce within 8-lane group.
// No LDS, no barriers. 64 partials/(b,g,h) to ws.
// ---------------------------------------------------------------------------
__global__ __launch_bounds__(512, 2) void attn3_kernel(
    const float* __restrict__ qc_g, const float* __restrict__ kn_g,
    const float* __restrict__ vn_g,
    const float* __restrict__ cache_k, const float* __restrict__ cache_v,
    float* __restrict__ pmss, float* __restrict__ pacc)
{
    const int t = threadIdx.x;
    const int wave = t >> 6, lane = t & 63;
    const int g8 = lane >> 3, j = lane & 7;
    const int b = blockIdx.x >> 3, split = blockIdx.x & 7;
    const int base = split * 512 + wave * 64;

    // q fragments: 4 heads x 16 floats
    float4 q[4][4];
    const float* qb = qc_g + (size_t)b * 4096 + g8 * 512 + j * 4;
#pragma unroll
    for (int h = 0; h < 4; ++h)
#pragma unroll
        for (int p = 0; p < 4; ++p)
            q[h][p] = *(const float4*)(qb + h * 128 + p * 32);

    float m[4] = {-1e30f, -1e30f, -1e30f, -1e30f};
    float ss[4] = {0.f, 0.f, 0.f, 0.f};
    float4 acc[4][4];
#pragma unroll
    for (int h = 0; h < 4; ++h)
#pragma unroll
        for (int p = 0; p < 4; ++p) acc[h][p] = make_float4(0.f, 0.f, 0.f, 0.f);

    auto process = [&](const float4* kf, const float4* vf) {
#pragma unroll
        for (int h = 0; h < 4; ++h) {
            float d = 0.f;
#pragma unroll
            for (int p = 0; p < 4; ++p) {
                d = fmaf(q[h][p].x, kf[p].x, d);
                d = fmaf(q[h][p].y, kf[p].y, d);
                d = fmaf(q[h][p].z, kf[p].z, d);
                d = fmaf(q[h][p].w, kf[p].w, d);
            }
            d += __shfl_xor(d, 1);
            d += __shfl_xor(d, 2);
            d += __shfl_xor(d, 4);
            const float dd = d - m[h];
            float pe;
            if (dd > 8.0f) {                       // rare: new max by margin
                const float c = __expf(-dd);
                ss[h] = fmaf(ss[h], c, 1.0f);
#pragma unroll
                for (int p = 0; p < 4; ++p) {
                    acc[h][p].x *= c; acc[h][p].y *= c;
                    acc[h][p].z *= c; acc[h][p].w *= c;
                }
                m[h] = d; pe = 1.0f;
            } else {
                pe = __expf(dd);                   // <= e^8
                ss[h] += pe;
            }
#pragma unroll
            for (int p = 0; p < 4; ++p) {
                acc[h][p].x = fmaf(pe, vf[p].x, acc[h][p].x);
                acc[h][p].y = fmaf(pe, vf[p].y, acc[h][p].y);
                acc[h][p].z = fmaf(pe, vf[p].z, acc[h][p].z);
                acc[h][p].w = fmaf(pe, vf[p].w, acc[h][p].w);
            }
        }
    };

    const float* kp = cache_k + ((size_t)b * 4096 + base) * 1024 + g8 * 128 + j * 4;
    const float* vp = cache_v + ((size_t)b * 4096 + base) * 1024 + g8 * 128 + j * 4;

    int nIter = 64;
    if (base + 63 == 4095) {          // wave 7 of split 7: new token first
        nIter = 63;
        float4 kf[4], vf[4];
        const float* kn = kn_g + (size_t)b * 1024 + g8 * 128 + j * 4;
        const float* vn = vn_g + (size_t)b * 1024 + g8 * 128 + j * 4;
#pragma unroll
        for (int p = 0; p < 4; ++p) {
            kf[p] = *(const float4*)(kn + p * 32);
            vf[p] = *(const float4*)(vn + p * 32);
        }
        process(kf, vf);
    }

    // 2-deep software pipeline over rows
    float4 ka[4], va[4], kb[4], vb[4];
#pragma unroll
    for (int p = 0; p < 4; ++p) {
        ka[p] = *(const float4*)(kp + p * 32);
        va[p] = *(const float4*)(vp + p * 32);
    }
    int i = 0;
    for (; i + 2 <= nIter; i += 2) {
        const float* k1 = kp + (size_t)(i + 1) * 1024;
        const float* v1 = vp + (size_t)(i + 1) * 1024;
#pragma unroll
        for (int p = 0; p < 4; ++p) {
            kb[p] = *(const float4*)(k1 + p * 32);
            vb[p] = *(const float4*)(v1 + p * 32);
        }
        process(ka, va);
        if (i + 2 < nIter) {
            const float* k2 = kp + (size_t)(i + 2) * 1024;
            const float* v2 = vp + (size_t)(i + 2) * 1024;
#pragma unroll
            for (int p = 0; p < 4; ++p) {
                ka[p] = *(const float4*)(k2 + p * 32);
                va[p] = *(const float4*)(v2 + p * 32);
            }
        }
        process(kb, vb);
    }
    if (i < nIter) process(ka, va);

    // write partials: idx = ((b*8+split)*8+wave)*32 + g8*4 + h
    const int pidx = ((b * 8 + split) * 8 + wave) * 32 + g8 * 4;
#pragma unroll
    for (int h = 0; h < 4; ++h) {
        float* pr = pacc + (size_t)(pidx + h) * 128 + j * 4;
#pragma unroll
        for (int p = 0; p < 4; ++p)
            *(float4*)(pr + p * 32) = acc[h][p];
    }
    if (j == 0) {
#pragma unroll
        for (int h = 0; h < 4; ++h) {
            pmss[(size_t)(pidx + h) * 2]     = m[h];
            pmss[(size_t)(pidx + h) * 2 + 1] = ss[h];
        }
    }
}

// ---------------------------------------------------------------------------
// Merge 64 partials per (b,g,h). Block=(b,g), 128 thr: h=t>>5, jj=t&31.
// ---------------------------------------------------------------------------
__global__ __launch_bounds__(128) void attn_combine_kernel(
    const float* __restrict__ pmss, const float* __restrict__ pacc,
    float* __restrict__ a_ws)
{
    const int bg = blockIdx.x, t = threadIdx.x;
    const int h = t >> 5, jj = t & 31;
    const int b = bg >> 3, g = bg & 7;

    float M = -1e30f;
#pragma unroll
    for (int sw = 0; sw < 64; ++sw) {
        const int idx = (bg * 8 + (sw >> 3)) * 8 * 32 - bg * 8 * 32 * 8 + 0; // placeholder
        (void)idx;
    }
    // recompute cleanly: idx = ((b*8+s)*8+w)*32 + g*4 + h = (bg would mix) ...
    // pass 1: global max
#pragma unroll
    for (int s = 0; s < 8; ++s)
#pragma unroll
        for (int w = 0; w < 8; ++w) {
            const int idx = (((b * 8 + s) * 8) + w) * 32 + g * 4 + h;
            M = fmaxf(M, pmss[(size_t)idx * 2]);
        }
    // pass 2: weighted sums
    float SS = 0.f;
    float4 o = make_float4(0.f, 0.f, 0.f, 0.f);
#pragma unroll
    for (int s = 0; s < 8; ++s)
#pragma unroll
        for (int w = 0; w < 8; ++w) {
            const int idx = (((b * 8 + s) * 8) + w) * 32 + g * 4 + h;
            const float wgt = __expf(pmss[(size_t)idx * 2] - M);
            SS = fmaf(pmss[(size_t)idx * 2 + 1], wgt, SS);
            const float4 a = *(const float4*)(pacc + (size_t)idx * 128 + jj * 4);
            o.x = fmaf(a.x, wgt, o.x);
            o.y = fmaf(a.y, wgt, o.y);
            o.z = fmaf(a.z, wgt, o.z);
            o.w = fmaf(a.w, wgt, o.w);
        }
    const float inv = 1.f / SS;
    o.x *= inv; o.y *= inv; o.z *= inv; o.w *= inv;
    *(float4*)(a_ws + (size_t)b * 4096 + (size_t)(g * 4 + h) * 128 + jj * 4) = o;
}

__global__ __launch_bounds__(256) void out_combine_kernel(
    const float* __restrict__ part, float* __restrict__ out)
{
    const int i4 = (blockIdx.x * 256 + threadIdx.x) * 4;
    float4 v = make_float4(0.f, 0.f, 0.f, 0.f);
#pragma unroll
    for (int s = 0; s < 16; ++s) {
        const float4 a = *(const float4*)(part + (size_t)s * 131072 + i4);
        v.x += a.x; v.y += a.y; v.z += a.z; v.w += a.w;
    }
    *(float4*)(out + i4) = v;
}

extern "C" void kernel_launch(void* const* d_in, const int* in_sizes, int n_in,
                              void* d_out, int out_size, void* d_ws, size_t ws_size,
                              hipStream_t stream)
{
    const float* x       = (const float*)d_in[0];
    const float* freqs   = (const float*)d_in[1];
    const float* cache_k = (const float*)d_in[2];
    const float* cache_v = (const float*)d_in[3];
    const float* wq      = (const float*)d_in[4];
    const float* wk      = (const float*)d_in[5];
    const float* wv      = (const float*)d_in[6];
    const float* wo      = (const float*)d_in[7];

    float* out = (float*)d_out;
    float* ws  = (float*)d_ws;
    float* part_qkv = ws;                    // 3145728
    float* qc_g     = ws + 3145728;          // 131072
    float* kn_g     = ws + 3276800;          // 32768
    float* vn_g     = ws + 3309568;          // 32768
    float* pmss     = ws + 3342336;          // 131072
    float* pacc     = ws + 3473408;          // 8388608
    float* a_ws     = ws + 11862016;         // 131072
    float* part_out = ws + 11993088;         // 2097152

    gemv_qkv_kernel<<<1536, 256, 0, stream>>>(wq, wk, wv, x, part_qkv);
    qkv_combine_kernel<<<192, 256, 0, stream>>>(part_qkv, freqs, qc_g, kn_g, vn_g);
    attn3_kernel<<<256, 512, 0, stream>>>(qc_g, kn_g, vn_g, cache_k, cache_v, pmss, pacc);
    attn_combine_kernel<<<256, 128, 0, stream>>>(pmss, pacc, a_ws);
    gemv_out_kernel<<<1024, 256, 0, stream>>>(wo, a_ws, part_out);
    out_combine_kernel<<<128, 256, 0, stream>>>(part_out, out);
}

// Round 4
// 330.826 us; speedup vs baseline: 1.2846x; 1.0586x over previous
//
#include <hip/hip_runtime.h>

// B=32, DIM=4096, NH=32, NKV=8, HD=128, MAXLEN=4096, START_POS=4095. All fp32.
// HBM floor: KV 1GB + weights 160MB ~= 190us @6.3TB/s.
#define QSCALE 0.08838834764831845f   // 1/sqrt(128)

// ws layout (floats):
//  part_qkv [16][32][6144] @ 0          (3145728)
//  qc_g     [32][4096]     @ 3145728    (131072)   roped+scaled q
//  kn_g     [32][1024]     @ 3276800    (32768)    roped new k
//  vn_g     [32][1024]     @ 3309568    (32768)    new v
//  pmss     [32768][2]     @ 3342336    (65536)
//  pacc     [32768][128]   @ 3407872    (4194304)
//  a_ws     [32][4096]     @ 7602176    (131072)
//  part_out [16][32][4096] @ 7733248    (2097152)

// ---------------------------------------------------------------------------
// GEMV: part[ks][n][m0+..] = sum over 256-k slice of W[m][k]*X[n][k].
// (unchanged from round 3)
// ---------------------------------------------------------------------------
#define GEMM_FMA(r, wf) \
    acc[r][0] = fmaf(wf.x, x0.x, acc[r][0]); acc[r][0] = fmaf(wf.y, x0.y, acc[r][0]); \
    acc[r][0] = fmaf(wf.z, x0.z, acc[r][0]); acc[r][0] = fmaf(wf.w, x0.w, acc[r][0]); \
    acc[r][1] = fmaf(wf.x, x1.x, acc[r][1]); acc[r][1] = fmaf(wf.y, x1.y, acc[r][1]); \
    acc[r][1] = fmaf(wf.z, x1.z, acc[r][1]); acc[r][1] = fmaf(wf.w, x1.w, acc[r][1]); \
    acc[r][2] = fmaf(wf.x, x2.x, acc[r][2]); acc[r][2] = fmaf(wf.y, x2.y, acc[r][2]); \
    acc[r][2] = fmaf(wf.z, x2.z, acc[r][2]); acc[r][2] = fmaf(wf.w, x2.w, acc[r][2]); \
    acc[r][3] = fmaf(wf.x, x3.x, acc[r][3]); acc[r][3] = fmaf(wf.y, x3.y, acc[r][3]); \
    acc[r][3] = fmaf(wf.z, x3.z, acc[r][3]); acc[r][3] = fmaf(wf.w, x3.w, acc[r][3]);

__device__ __forceinline__ void gemv3(
    const float* __restrict__ W,      // pre-offset: row 0 == output column m0
    const float* __restrict__ X,
    float* __restrict__ part, const int M, const int m0, const int ks)
{
    const int t = threadIdx.x;
    const int ksub = t & 3;
    const int ngrp = (t >> 2) & 7;
    const int mgrp = t >> 5;

    const int kbase = ks * 256 + ksub * 4;
    const float* wr0 = W + (size_t)(mgrp * 8 + 0) * 4096 + kbase;
    const float* wr1 = W + (size_t)(mgrp * 8 + 1) * 4096 + kbase;
    const float* wr2 = W + (size_t)(mgrp * 8 + 2) * 4096 + kbase;
    const float* wr3 = W + (size_t)(mgrp * 8 + 3) * 4096 + kbase;
    const float* wr4 = W + (size_t)(mgrp * 8 + 4) * 4096 + kbase;
    const float* wr5 = W + (size_t)(mgrp * 8 + 5) * 4096 + kbase;
    const float* wr6 = W + (size_t)(mgrp * 8 + 6) * 4096 + kbase;
    const float* wr7 = W + (size_t)(mgrp * 8 + 7) * 4096 + kbase;
    const float* xr0 = X + (size_t)(ngrp * 4 + 0) * 4096 + kbase;
    const float* xr1 = X + (size_t)(ngrp * 4 + 1) * 4096 + kbase;
    const float* xr2 = X + (size_t)(ngrp * 4 + 2) * 4096 + kbase;
    const float* xr3 = X + (size_t)(ngrp * 4 + 3) * 4096 + kbase;

    float acc[8][4];
#pragma unroll
    for (int r = 0; r < 8; ++r)
#pragma unroll
        for (int n = 0; n < 4; ++n) acc[r][n] = 0.f;

#pragma unroll 2
    for (int c = 0; c < 16; ++c) {
        const int off = c * 16;
        const float4 w0 = *(const float4*)(wr0 + off);
        const float4 w1 = *(const float4*)(wr1 + off);
        const float4 w2 = *(const float4*)(wr2 + off);
        const float4 w3 = *(const float4*)(wr3 + off);
        const float4 w4 = *(const float4*)(wr4 + off);
        const float4 w5 = *(const float4*)(wr5 + off);
        const float4 w6 = *(const float4*)(wr6 + off);
        const float4 w7 = *(const float4*)(wr7 + off);
        const float4 x0 = *(const float4*)(xr0 + off);
        const float4 x1 = *(const float4*)(xr1 + off);
        const float4 x2 = *(const float4*)(xr2 + off);
        const float4 x3 = *(const float4*)(xr3 + off);
        GEMM_FMA(0, w0) GEMM_FMA(1, w1) GEMM_FMA(2, w2) GEMM_FMA(3, w3)
        GEMM_FMA(4, w4) GEMM_FMA(5, w5) GEMM_FMA(6, w6) GEMM_FMA(7, w7)
    }

#pragma unroll
    for (int r = 0; r < 8; ++r)
#pragma unroll
        for (int n = 0; n < 4; ++n) {
            acc[r][n] += __shfl_xor(acc[r][n], 1);
            acc[r][n] += __shfl_xor(acc[r][n], 2);
        }

    if (ksub == 0) {
        float* base = part + (size_t)ks * 32 * M + m0 + mgrp * 8;
#pragma unroll
        for (int n = 0; n < 4; ++n) {
            float* dst = base + (size_t)(ngrp * 4 + n) * M;
            *(float4*)(dst)     = make_float4(acc[0][n], acc[1][n], acc[2][n], acc[3][n]);
            *(float4*)(dst + 4) = make_float4(acc[4][n], acc[5][n], acc[6][n], acc[7][n]);
        }
    }
}

__global__ __launch_bounds__(256, 4) void gemv_qkv_kernel(
    const float* __restrict__ wq, const float* __restrict__ wk,
    const float* __restrict__ wv, const float* __restrict__ x,
    float* __restrict__ part)     // [16][32][6144]
{
    const int mb = blockIdx.x >> 4, ks = blockIdx.x & 15;
    const int m0 = mb * 64;
    const float* W;
    if (m0 < 4096)      W = wq + (size_t)m0 * 4096;
    else if (m0 < 5120) W = wk + (size_t)(m0 - 4096) * 4096;
    else                W = wv + (size_t)(m0 - 5120) * 4096;
    gemv3(W, x, part, 6144, m0, ks);
}

__global__ __launch_bounds__(256, 4) void gemv_out_kernel(
    const float* __restrict__ wo, const float* __restrict__ a_ws,
    float* __restrict__ part)     // [16][32][4096]
{
    const int mb = blockIdx.x >> 4, ks = blockIdx.x & 15;
    gemv3(wo + (size_t)(mb * 64) * 4096, a_ws, part, 4096, mb * 64, ks);
}

// ---------------------------------------------------------------------------
// qkv combine: sum 16 k-split partials; rope+scale q, rope new k, copy new v.
// ---------------------------------------------------------------------------
__global__ __launch_bounds__(256) void qkv_combine_kernel(
    const float* __restrict__ part,   // [16][32][6144]
    const float* __restrict__ freqs,  // [128]
    float* __restrict__ qc_g, float* __restrict__ kn_g, float* __restrict__ vn_g)
{
    const int idx = blockIdx.x * 256 + threadIdx.x;   // f4 index, 49152 total
    const int b = idx / 1536;
    const int cm = (idx - b * 1536) * 4;              // column within 6144
    const float* p = part + (size_t)b * 6144 + cm;
    float4 v = make_float4(0.f, 0.f, 0.f, 0.f);
#pragma unroll
    for (int s = 0; s < 16; ++s) {
        const float4 a = *(const float4*)(p + (size_t)s * (32 * 6144));
        v.x += a.x; v.y += a.y; v.z += a.z; v.w += a.w;
    }
    if (cm < 4096) {
        const int d = cm & 127;
        const float4 f = *(const float4*)(freqs + d);
        float4 o;
        o.x = (v.x * f.x - v.y * f.y) * QSCALE;
        o.y = (v.x * f.y + v.y * f.x) * QSCALE;
        o.z = (v.z * f.z - v.w * f.w) * QSCALE;
        o.w = (v.z * f.w + v.w * f.z) * QSCALE;
        *(float4*)(qc_g + (size_t)b * 4096 + cm) = o;
    } else if (cm < 5120) {
        const int d = (cm - 4096) & 127;
        const float4 f = *(const float4*)(freqs + d);
        float4 o;
        o.x = v.x * f.x - v.y * f.y;
        o.y = v.x * f.y + v.y * f.x;
        o.z = v.z * f.z - v.w * f.w;
        o.w = v.z * f.w + v.w * f.z;
        *(float4*)(kn_g + (size_t)b * 1024 + (cm - 4096)) = o;
    } else {
        *(float4*)(vn_g + (size_t)b * 1024 + (cm - 5120)) = v;
    }
}

// ---------------------------------------------------------------------------
// Attention v4: 32-lane row-chunk groups, ~80 VGPR, ~24 waves/CU.
// grid = 1024 blocks: bid = (b*16 + split)*2 + q2. Block = 256 thr = 4 waves.
// Wave w: gsub = w>>1, rsub = w&1. Lane: g2 = lane>>5, j = lane&31.
// Chunk g = q2*4 + gsub*2 + g2 (kv-group). Lane owns d-slice j*4..j*4+4.
// Wave streams rows [split*256 + rsub*128, +128), reading 2 x 512B contiguous
// segments (K) + 2 (V) per row. Dot: 5-level shfl over 32-lane group.
// Online softmax w/ deferred rescale; 3-deep K/V prefetch. No LDS/barriers.
// ---------------------------------------------------------------------------
__global__ __launch_bounds__(256, 4) void attn4_kernel(
    const float* __restrict__ qc_g, const float* __restrict__ kn_g,
    const float* __restrict__ vn_g,
    const float* __restrict__ cache_k, const float* __restrict__ cache_v,
    float* __restrict__ pmss, float* __restrict__ pacc)
{
    const int t = threadIdx.x;
    const int w = t >> 6, lane = t & 63;
    const int g2 = lane >> 5, j = lane & 31;
    const int bid = blockIdx.x;
    const int q2 = bid & 1, split = (bid >> 1) & 15, b = bid >> 5;
    const int gsub = w >> 1, rsub = w & 1;
    const int g = q2 * 4 + gsub * 2 + g2;
    const int row0 = split * 256 + rsub * 128;

    // q fragments: 4 heads x 1 float4
    float4 q[4];
    const float* qb = qc_g + (size_t)b * 4096 + (size_t)g * 512 + j * 4;
#pragma unroll
    for (int h = 0; h < 4; ++h) q[h] = *(const float4*)(qb + h * 128);

    float m[4]  = {-1e30f, -1e30f, -1e30f, -1e30f};
    float ss[4] = {0.f, 0.f, 0.f, 0.f};
    float4 acc[4];
#pragma unroll
    for (int h = 0; h < 4; ++h) acc[h] = make_float4(0.f, 0.f, 0.f, 0.f);

    auto process = [&](const float4 kf, const float4 vf) {
        float d[4];
#pragma unroll
        for (int h = 0; h < 4; ++h)
            d[h] = fmaf(q[h].x, kf.x, fmaf(q[h].y, kf.y,
                   fmaf(q[h].z, kf.z, q[h].w * kf.w)));
#pragma unroll
        for (int mask = 1; mask <= 16; mask <<= 1) {
            d[0] += __shfl_xor(d[0], mask);
            d[1] += __shfl_xor(d[1], mask);
            d[2] += __shfl_xor(d[2], mask);
            d[3] += __shfl_xor(d[3], mask);
        }
#pragma unroll
        for (int h = 0; h < 4; ++h) {
            const float dd = d[h] - m[h];
            float pe;
            if (dd > 8.0f) {                       // rare: new max by margin
                const float c = __expf(-dd);
                ss[h] = fmaf(ss[h], c, 1.0f);
                acc[h].x *= c; acc[h].y *= c; acc[h].z *= c; acc[h].w *= c;
                m[h] = d[h]; pe = 1.0f;
            } else {
                pe = __expf(dd);                   // <= e^8
                ss[h] += pe;
            }
            acc[h].x = fmaf(pe, vf.x, acc[h].x);
            acc[h].y = fmaf(pe, vf.y, acc[h].y);
            acc[h].z = fmaf(pe, vf.z, acc[h].z);
            acc[h].w = fmaf(pe, vf.w, acc[h].w);
        }
    };

    const size_t cbase = ((size_t)b * 4096 + row0) * 1024 + (size_t)g * 128 + j * 4;
    const float* kp = cache_k + cbase;
    const float* vp = cache_v + cbase;

    const bool lastw = (split == 15) && (rsub == 1);   // owns row 4095
    const int n = lastw ? 127 : 128;

    // 3-deep pipeline (2 rows ahead)
    float4 kA = *(const float4*)(kp);
    float4 vA = *(const float4*)(vp);
    float4 kB = *(const float4*)(kp + 1024);
    float4 vB = *(const float4*)(vp + 1024);
#pragma unroll 2
    for (int i = 0; i < n; ++i) {
        float4 kC, vC;
        if (i + 2 < n) {
            kC = *(const float4*)(kp + (size_t)(i + 2) * 1024);
            vC = *(const float4*)(vp + (size_t)(i + 2) * 1024);
        }
        process(kA, vA);
        kA = kB; vA = vB; kB = kC; vB = vC;
    }
    if (lastw) {   // row 4095: freshly roped new-token k / new v
        const float4 kf = *(const float4*)(kn_g + (size_t)b * 1024 + (size_t)g * 128 + j * 4);
        const float4 vf = *(const float4*)(vn_g + (size_t)b * 1024 + (size_t)g * 128 + j * 4);
        process(kf, vf);
    }

    // partials: idx = (((b*16+split)*2+rsub)*8 + g)*4 + h
    const int pidx = (((b * 16 + split) * 2 + rsub) * 8 + g) * 4;
#pragma unroll
    for (int h = 0; h < 4; ++h)
        *(float4*)(pacc + (size_t)(pidx + h) * 128 + j * 4) = acc[h];
    if (j == 0) {
#pragma unroll
        for (int h = 0; h < 4; ++h) {
            pmss[(size_t)(pidx + h) * 2]     = m[h];
            pmss[(size_t)(pidx + h) * 2 + 1] = ss[h];
        }
    }
}

// ---------------------------------------------------------------------------
// Merge 32 partials per (b,g,h). Block=(b,g), 128 thr: h=t>>5, jj=t&31.
// ---------------------------------------------------------------------------
__global__ __launch_bounds__(128) void attn_combine_kernel(
    const float* __restrict__ pmss, const float* __restrict__ pacc,
    float* __restrict__ a_ws)
{
    const int bg = blockIdx.x, t = threadIdx.x;
    const int h = t >> 5, jj = t & 31;
    const int b = bg >> 3, g = bg & 7;

    float M = -1e30f;
#pragma unroll
    for (int s = 0; s < 16; ++s)
#pragma unroll
        for (int r = 0; r < 2; ++r) {
            const int idx = (((b * 16 + s) * 2 + r) * 8 + g) * 4 + h;
            M = fmaxf(M, pmss[(size_t)idx * 2]);
        }
    float SS = 0.f;
    float4 o = make_float4(0.f, 0.f, 0.f, 0.f);
#pragma unroll
    for (int s = 0; s < 16; ++s)
#pragma unroll
        for (int r = 0; r < 2; ++r) {
            const int idx = (((b * 16 + s) * 2 + r) * 8 + g) * 4 + h;
            const float wgt = __expf(pmss[(size_t)idx * 2] - M);
            SS = fmaf(pmss[(size_t)idx * 2 + 1], wgt, SS);
            const float4 a = *(const float4*)(pacc + (size_t)idx * 128 + jj * 4);
            o.x = fmaf(a.x, wgt, o.x);
            o.y = fmaf(a.y, wgt, o.y);
            o.z = fmaf(a.z, wgt, o.z);
            o.w = fmaf(a.w, wgt, o.w);
        }
    const float inv = 1.f / SS;
    o.x *= inv; o.y *= inv; o.z *= inv; o.w *= inv;
    *(float4*)(a_ws + (size_t)b * 4096 + (size_t)(g * 4 + h) * 128 + jj * 4) = o;
}

__global__ __launch_bounds__(256) void out_combine_kernel(
    const float* __restrict__ part, float* __restrict__ out)
{
    const int i4 = (blockIdx.x * 256 + threadIdx.x) * 4;
    float4 v = make_float4(0.f, 0.f, 0.f, 0.f);
#pragma unroll
    for (int s = 0; s < 16; ++s) {
        const float4 a = *(const float4*)(part + (size_t)s * 131072 + i4);
        v.x += a.x; v.y += a.y; v.z += a.z; v.w += a.w;
    }
    *(float4*)(out + i4) = v;
}

extern "C" void kernel_launch(void* const* d_in, const int* in_sizes, int n_in,
                              void* d_out, int out_size, void* d_ws, size_t ws_size,
                              hipStream_t stream)
{
    const float* x       = (const float*)d_in[0];
    const float* freqs   = (const float*)d_in[1];
    const float* cache_k = (const float*)d_in[2];
    const float* cache_v = (const float*)d_in[3];
    const float* wq      = (const float*)d_in[4];
    const float* wk      = (const float*)d_in[5];
    const float* wv      = (const float*)d_in[6];
    const float* wo      = (const float*)d_in[7];

    float* out = (float*)d_out;
    float* ws  = (float*)d_ws;
    float* part_qkv = ws;                    // 3145728
    float* qc_g     = ws + 3145728;          // 131072
    float* kn_g     = ws + 3276800;          // 32768
    float* vn_g     = ws + 3309568;          // 32768
    float* pmss     = ws + 3342336;          // 65536
    float* pacc     = ws + 3407872;          // 4194304
    float* a_ws     = ws + 7602176;          // 131072
    float* part_out = ws + 7733248;          // 2097152

    gemv_qkv_kernel<<<1536, 256, 0, stream>>>(wq, wk, wv, x, part_qkv);
    qkv_combine_kernel<<<192, 256, 0, stream>>>(part_qkv, freqs, qc_g, kn_g, vn_g);
    attn4_kernel<<<1024, 256, 0, stream>>>(qc_g, kn_g, vn_g, cache_k, cache_v, pmss, pacc);
    attn_combine_kernel<<<256, 128, 0, stream>>>(pmss, pacc, a_ws);
    gemv_out_kernel<<<1024, 256, 0, stream>>>(wo, a_ws, part_out);
    out_combine_kernel<<<128, 256, 0, stream>>>(part_out, out);
}